// Round 1
// baseline (2550.613 us; speedup 1.0000x reference)
//
#include <hip/hip_runtime.h>
#include <cmath>

namespace {

constexpr int B = 64, N = 5000, DIN = 64, DMID = 128, DOUT = 32, E = 80000;
constexpr int TILE = 8;

__global__ void zero_kernel(int* counts, int* fill, float* msum) {
  int i = blockIdx.x * 256 + threadIdx.x;
  if (i < N) { counts[i] = 0; fill[i] = 0; }
  if (i < B * DMID) msum[i] = 0.f;
}

__global__ void count_kernel(const int* __restrict__ ei, int* counts) {
  int e = blockIdx.x * 256 + threadIdx.x;
  if (e < E) atomicAdd(&counts[ei[E + e]], 1);
}

// Single-block exclusive scan over counts -> rowptr, plus dis = rsqrt(deg).
__global__ void scan_kernel(const int* __restrict__ counts, int* rowptr, float* dis) {
  __shared__ int sdata[1024];
  const int tid = threadIdx.x;
  constexpr int CH = (N + 1023) / 1024;  // 5
  int local[CH];
  int s = 0;
  for (int i = 0; i < CH; i++) {
    int idx = tid * CH + i;
    int c = (idx < N) ? counts[idx] : 0;
    local[i] = s;
    s += c;
  }
  sdata[tid] = s;
  __syncthreads();
  for (int off = 1; off < 1024; off <<= 1) {
    int v = (tid >= off) ? sdata[tid - off] : 0;
    __syncthreads();
    sdata[tid] += v;
    __syncthreads();
  }
  int prev = (tid > 0) ? sdata[tid - 1] : 0;
  for (int i = 0; i < CH; i++) {
    int idx = tid * CH + i;
    if (idx < N) {
      rowptr[idx] = prev + local[i];
      // deg = in-degree(by col) + 1 (self loop); always > 0
      dis[idx] = rsqrtf((float)(counts[idx] + 1));
    }
  }
  if (tid == 1023) rowptr[N] = sdata[1023];
}

__global__ void fill_kernel(const int* __restrict__ ei, const int* __restrict__ rowptr,
                            const float* __restrict__ dis, int* fill,
                            int* csr_src, float* csr_w) {
  int e = blockIdx.x * 256 + threadIdx.x;
  if (e >= E) return;
  int r = ei[e], c = ei[E + e];
  int pos = rowptr[c] + atomicAdd(&fill[c], 1);
  csr_src[pos] = r;
  csr_w[pos] = dis[r] * dis[c];
}

// xs[b,n,:] = sum_{e: col==n} x[b,row(e),:]*w(e) + x[b,n,:]*dis[n]^2
__global__ void agg_kernel(const float* __restrict__ x, const int* __restrict__ rowptr,
                           const int* __restrict__ csr_src, const float* __restrict__ csr_w,
                           const float* __restrict__ dis, float* __restrict__ xs) {
  const int n = blockIdx.x, b = blockIdx.y, t = threadIdx.x;  // 64 threads = DIN
  const float* xb = x + (size_t)b * N * DIN;
  float d = dis[n];
  float acc = xb[(size_t)n * DIN + t] * d * d;
  const int s0 = rowptr[n], s1 = rowptr[n + 1];
  for (int p = s0; p < s1; p++)
    acc = fmaf(xb[(size_t)csr_src[p] * DIN + t], csr_w[p], acc);
  xs[((size_t)b * N + n) * DIN + t] = acc;
}

__global__ __launch_bounds__(128) void fused_kernel(
    const float* __restrict__ xs, const float* __restrict__ H,
    const float* __restrict__ Wgz, const float* __restrict__ bgz,
    const float* __restrict__ Wgr, const float* __restrict__ bgr,
    const float* __restrict__ Wgh, const float* __restrict__ bgh,
    const float* __restrict__ Wlz, const float* __restrict__ blz,
    const float* __restrict__ Wlr, const float* __restrict__ blr,
    const float* __restrict__ Wlh, const float* __restrict__ blh,
    float* __restrict__ hnew, float* __restrict__ msum) {
  __shared__ float xs_t[TILE][DIN];
  __shared__ float H_t[TILE][DMID];
  __shared__ float conv_t[3][TILE][DMID];
  __shared__ float r_t[TILE][DMID];

  const int tid = threadIdx.x;
  const int b = blockIdx.y;
  const int n0 = blockIdx.x * TILE;

  const float* xsb = xs + ((size_t)b * N + n0) * DIN;
  const float* Hb = H + ((size_t)b * N + n0) * DMID;
  for (int idx = tid; idx < TILE * DIN; idx += 128) ((float*)xs_t)[idx] = xsb[idx];
  for (int idx = tid; idx < TILE * DMID; idx += 128) ((float*)H_t)[idx] = Hb[idx];
  __syncthreads();

  const int j = tid;  // output feature owned by this thread
  const float* Wg[3] = {Wgz, Wgr, Wgh};
  const float* bgp[3] = {bgz, bgr, bgh};

  // Phase 1: conv_g = xs @ Wg_g + bg_g  (64 -> 128), g in {z,r,h}
  for (int g = 0; g < 3; g++) {
    float acc[TILE];
    const float bias = bgp[g][j];
#pragma unroll
    for (int i = 0; i < TILE; i++) acc[i] = bias;
    const float* W = Wg[g];
    for (int k = 0; k < DIN; k++) {
      float w = W[k * DMID + j];
#pragma unroll
      for (int i = 0; i < TILE; i++) acc[i] = fmaf(xs_t[i][k], w, acc[i]);
    }
#pragma unroll
    for (int i = 0; i < TILE; i++) conv_t[g][i][j] = acc[i];
  }
  __syncthreads();

  // Phase 2: z gate (kept in registers) and r gate (to LDS)
  float zreg[TILE];
  {
    float acc[TILE];
    const float bias = blz[j];
#pragma unroll
    for (int i = 0; i < TILE; i++) acc[i] = bias;
    for (int k = 0; k < DMID; k++) {
      float w = Wlz[k * DMID + j];
#pragma unroll
      for (int i = 0; i < TILE; i++) acc[i] = fmaf(conv_t[0][i][k], w, acc[i]);
    }
    for (int k = 0; k < DMID; k++) {
      float w = Wlz[(DMID + k) * DMID + j];
#pragma unroll
      for (int i = 0; i < TILE; i++) acc[i] = fmaf(H_t[i][k], w, acc[i]);
    }
#pragma unroll
    for (int i = 0; i < TILE; i++) zreg[i] = 1.f / (1.f + expf(-acc[i]));
  }
  {
    float acc[TILE];
    const float bias = blr[j];
#pragma unroll
    for (int i = 0; i < TILE; i++) acc[i] = bias;
    for (int k = 0; k < DMID; k++) {
      float w = Wlr[k * DMID + j];
#pragma unroll
      for (int i = 0; i < TILE; i++) acc[i] = fmaf(conv_t[1][i][k], w, acc[i]);
    }
    for (int k = 0; k < DMID; k++) {
      float w = Wlr[(DMID + k) * DMID + j];
#pragma unroll
      for (int i = 0; i < TILE; i++) acc[i] = fmaf(H_t[i][k], w, acc[i]);
    }
#pragma unroll
    for (int i = 0; i < TILE; i++) r_t[i][j] = 1.f / (1.f + expf(-acc[i]));
  }
  __syncthreads();

  // Phase 3: h gate, H_new, mean accumulation
  {
    float acc[TILE];
    const float bias = blh[j];
#pragma unroll
    for (int i = 0; i < TILE; i++) acc[i] = bias;
    for (int k = 0; k < DMID; k++) {
      float w = Wlh[k * DMID + j];
#pragma unroll
      for (int i = 0; i < TILE; i++) acc[i] = fmaf(conv_t[2][i][k], w, acc[i]);
    }
    for (int k = 0; k < DMID; k++) {
      float w = Wlh[(DMID + k) * DMID + j];
#pragma unroll
      for (int i = 0; i < TILE; i++) acc[i] = fmaf(H_t[i][k] * r_t[i][k], w, acc[i]);
    }
    float lsum = 0.f;
#pragma unroll
    for (int i = 0; i < TILE; i++) {
      float ht = tanhf(acc[i]);
      float z = zreg[i];
      float hn = fmaf(z, H_t[i][j] - ht, ht);  // z*H + (1-z)*ht
      hnew[((size_t)b * N + n0 + i) * DMID + j] = hn;
      lsum += hn;
    }
    atomicAdd(&msum[b * DMID + j], lsum);
  }
}

// y[b,:] = relu(msum[b,:]/N) @ W_out + b_out
__global__ void out_kernel(const float* __restrict__ msum, const float* __restrict__ Wout,
                           const float* __restrict__ bout, float* __restrict__ y) {
  const int b = blockIdx.x;
  const int o = threadIdx.x;  // 32 threads
  __shared__ float m[DMID];
  for (int jj = o; jj < DMID; jj += 32)
    m[jj] = fmaxf(msum[b * DMID + jj] * (1.f / (float)N), 0.f);
  __syncthreads();
  float acc = bout[o];
  for (int jj = 0; jj < DMID; jj++)
    acc = fmaf(m[jj], Wout[jj * DOUT + o], acc);
  y[b * DOUT + o] = acc;
}

}  // namespace

extern "C" void kernel_launch(void* const* d_in, const int* in_sizes, int n_in,
                              void* d_out, int out_size, void* d_ws, size_t ws_size,
                              hipStream_t stream) {
  const float* x = (const float*)d_in[0];
  const int* ei = (const int*)d_in[1];
  const float* H = (const float*)d_in[2];
  const float* Wgz = (const float*)d_in[3];
  const float* bgz = (const float*)d_in[4];
  const float* Wgr = (const float*)d_in[5];
  const float* bgr = (const float*)d_in[6];
  const float* Wgh = (const float*)d_in[7];
  const float* bgh = (const float*)d_in[8];
  const float* Wlz = (const float*)d_in[9];
  const float* blz = (const float*)d_in[10];
  const float* Wlr = (const float*)d_in[11];
  const float* blr = (const float*)d_in[12];
  const float* Wlh = (const float*)d_in[13];
  const float* blh = (const float*)d_in[14];
  const float* Wout = (const float*)d_in[15];
  const float* bout = (const float*)d_in[16];

  float* y = (float*)d_out;                       // [B, DOUT] first in return order
  float* hnew = (float*)d_out + (size_t)B * DOUT; // [B, N, DMID]

  char* p = (char*)d_ws;
  auto carve = [&](size_t bytes) {
    char* q = p;
    p += (bytes + 255) & ~size_t(255);
    return q;
  };
  int* counts = (int*)carve((size_t)N * 4);
  int* rowptr = (int*)carve((size_t)(N + 1) * 4);
  int* fill = (int*)carve((size_t)N * 4);
  int* csr_src = (int*)carve((size_t)E * 4);
  float* csr_w = (float*)carve((size_t)E * 4);
  float* dis = (float*)carve((size_t)N * 4);
  float* msum = (float*)carve((size_t)B * DMID * 4);
  float* xs = (float*)carve((size_t)B * N * DIN * 4);  // ~82 MB

  zero_kernel<<<(B * DMID + 255) / 256, 256, 0, stream>>>(counts, fill, msum);
  count_kernel<<<(E + 255) / 256, 256, 0, stream>>>(ei, counts);
  scan_kernel<<<1, 1024, 0, stream>>>(counts, rowptr, dis);
  fill_kernel<<<(E + 255) / 256, 256, 0, stream>>>(ei, rowptr, dis, fill, csr_src, csr_w);
  agg_kernel<<<dim3(N, B), 64, 0, stream>>>(x, rowptr, csr_src, csr_w, dis, xs);
  fused_kernel<<<dim3(N / TILE, B), 128, 0, stream>>>(xs, H, Wgz, bgz, Wgr, bgr, Wgh, bgh,
                                                      Wlz, blz, Wlr, blr, Wlh, blh, hnew, msum);
  out_kernel<<<B, 32, 0, stream>>>(msum, Wout, bout, y);
}

// Round 2
// 1239.165 us; speedup vs baseline: 2.0583x; 2.0583x over previous
//
#include <hip/hip_runtime.h>
#include <cmath>

namespace {

constexpr int B = 64, N = 5000, DIN = 64, DMID = 128, DOUT = 32, E = 80000;

typedef unsigned short u16;
typedef __attribute__((ext_vector_type(8))) short short8;
typedef __attribute__((ext_vector_type(4))) float floatx4;

#define MFMA16(a, b, c) __builtin_amdgcn_mfma_f32_16x16x32_bf16((a), (b), (c), 0, 0, 0)

__device__ __forceinline__ u16 f2bf(float f) {
  union { float f; unsigned u; } v; v.f = f;
  unsigned r = v.u + 0x7FFFu + ((v.u >> 16) & 1u);  // RNE
  return (u16)(r >> 16);
}
__device__ __forceinline__ float bf2f(u16 s) {
  union { unsigned u; float f; } v; v.u = ((unsigned)s) << 16;
  return v.f;
}
__device__ __forceinline__ float sigmoid_fast(float x) {
  return __builtin_amdgcn_rcpf(1.f + __expf(-x));   // saturates cleanly at +-inf
}
__device__ __forceinline__ float tanh_fast(float x) {
  return fmaf(2.f, __builtin_amdgcn_rcpf(1.f + __expf(-2.f * x)), -1.f);
}

// ---------------- graph build (unchanged from R1, verified) ----------------

__global__ void zero_kernel(int* counts, int* fill, float* msum) {
  int i = blockIdx.x * 256 + threadIdx.x;
  if (i < N) { counts[i] = 0; fill[i] = 0; }
  if (i < B * DMID) msum[i] = 0.f;
}

__global__ void count_kernel(const int* __restrict__ ei, int* counts) {
  int e = blockIdx.x * 256 + threadIdx.x;
  if (e < E) atomicAdd(&counts[ei[E + e]], 1);
}

__global__ void scan_kernel(const int* __restrict__ counts, int* rowptr, float* dis) {
  __shared__ int sdata[1024];
  const int tid = threadIdx.x;
  constexpr int CH = (N + 1023) / 1024;  // 5
  int local[CH];
  int s = 0;
  for (int i = 0; i < CH; i++) {
    int idx = tid * CH + i;
    int c = (idx < N) ? counts[idx] : 0;
    local[i] = s;
    s += c;
  }
  sdata[tid] = s;
  __syncthreads();
  for (int off = 1; off < 1024; off <<= 1) {
    int v = (tid >= off) ? sdata[tid - off] : 0;
    __syncthreads();
    sdata[tid] += v;
    __syncthreads();
  }
  int prev = (tid > 0) ? sdata[tid - 1] : 0;
  for (int i = 0; i < CH; i++) {
    int idx = tid * CH + i;
    if (idx < N) {
      rowptr[idx] = prev + local[i];
      dis[idx] = rsqrtf((float)(counts[idx] + 1));  // + self loop
    }
  }
  if (tid == 1023) rowptr[N] = sdata[1023];
}

__global__ void fill_kernel(const int* __restrict__ ei, const int* __restrict__ rowptr,
                            const float* __restrict__ dis, int* fill,
                            int* csr_src, float* csr_w) {
  int e = blockIdx.x * 256 + threadIdx.x;
  if (e >= E) return;
  int r = ei[e], c = ei[E + e];
  int pos = rowptr[c] + atomicAdd(&fill[c], 1);
  csr_src[pos] = r;
  csr_w[pos] = dis[r] * dis[c];
}

// ---------------- weight packing into B-fragment-linear bf16 ----------------
// B-frag convention (16x16x32): lane l holds B[k = (l>>4)*8 + jj][n = l&15],
// jj ascending in memory (matches A-frags read linearly from LDS).
// wgB: conv weights, chunks c = kt*24 + (g*8 + nt), kt<2, nt<8, g<3
// wlB: gate weights, chunks c = g*64 + kt*8 + nt, kt<8, nt<8

__global__ void pack_kernel(const float* Wgz, const float* Wgr, const float* Wgh,
                            const float* Wlz, const float* Wlr, const float* Wlh,
                            const float* bgz, const float* bgr, const float* bgh,
                            const float* blz, const float* blr, const float* blh,
                            u16* wgB, u16* wlB, float* bgAll, float* blAll) {
  int t = blockIdx.x * 256 + threadIdx.x;
  const float* Wg[3] = {Wgz, Wgr, Wgh};
  const float* Wl[3] = {Wlz, Wlr, Wlh};
  const float* bg[3] = {bgz, bgr, bgh};
  const float* bl[3] = {blz, blr, blh};
  if (t < 240 * 64) {
    int chunk = t >> 6, lane = t & 63;
    int q = lane >> 4, lm = lane & 15;
    if (chunk < 48) {
      int kt = chunk / 24, ntg = chunk % 24, g = ntg >> 3, nt = ntg & 7;
#pragma unroll
      for (int jj = 0; jj < 8; jj++) {
        int k = kt * 32 + q * 8 + jj, n = nt * 16 + lm;
        wgB[(size_t)(chunk * 64 + lane) * 8 + jj] = f2bf(Wg[g][k * DMID + n]);
      }
    } else {
      int c = chunk - 48, g = c >> 6, rem = c & 63, kt = rem >> 3, nt = rem & 7;
#pragma unroll
      for (int jj = 0; jj < 8; jj++) {
        int k = kt * 32 + q * 8 + jj, n = nt * 16 + lm;
        wlB[(size_t)(c * 64 + lane) * 8 + jj] = f2bf(Wl[g][k * DMID + n]);
      }
    }
  } else {
    int t2 = t - 240 * 64;
    if (t2 < 384) bgAll[t2] = bg[t2 >> 7][t2 & 127];
    else if (t2 < 768) { int t3 = t2 - 384; blAll[t3] = bl[t3 >> 7][t3 & 127]; }
  }
}

// ---------------- aggregation: xs = S @ x, bf16 out ----------------

__global__ void agg_kernel(const float* __restrict__ x, const int* __restrict__ rowptr,
                           const int* __restrict__ csr_src, const float* __restrict__ csr_w,
                           const float* __restrict__ dis, u16* __restrict__ xs) {
  const int unit = blockIdx.x * 4 + (threadIdx.x >> 6);  // flat (b*N + n)
  const int lane = threadIdx.x & 63;
  const int b = unit / N;
  const int n = unit - b * N;
  const float* xb = x + (size_t)b * N * DIN;
  float d = dis[n];
  float acc = xb[(size_t)n * DIN + lane] * d * d;
  const int s0 = rowptr[n], s1 = rowptr[n + 1];
  for (int p = s0; p < s1; p++)
    acc = fmaf(xb[(size_t)csr_src[p] * DIN + lane], csr_w[p], acc);
  xs[(size_t)unit * DIN + lane] = f2bf(acc);
}

// ---------------- fused MFMA kernel ----------------
// Block: 128 threads = 2 waves; wave w owns rows [w*32, w*32+32) of a 64-row tile.
// LDS strides padded to 72/136 bf16 (16B-aligned rows, <=2-way bank aliasing).

constexpr int SH = 136;  // stride for 128-wide bf16 tiles
constexpr int SX = 72;   // stride for 64-wide bf16 tiles

__device__ __forceinline__ void conv_gemm(int g, const short8 ax[2][2],
                                          const u16* __restrict__ wgB,
                                          const float* __restrict__ bgAll,
                                          u16* CONV_s, int w32, int lane) {
  const int q = lane >> 4, lm = lane & 15;
#pragma unroll
  for (int nt = 0; nt < 8; nt++) {
    floatx4 c0 = {0.f, 0.f, 0.f, 0.f}, c1 = {0.f, 0.f, 0.f, 0.f};
    short8 b0 = *(const short8*)(wgB + (size_t)((0 * 24 + g * 8 + nt) * 64 + lane) * 8);
    short8 b1 = *(const short8*)(wgB + (size_t)((1 * 24 + g * 8 + nt) * 64 + lane) * 8);
    c0 = MFMA16(ax[0][0], b0, c0);
    c0 = MFMA16(ax[0][1], b1, c0);
    c1 = MFMA16(ax[1][0], b0, c1);
    c1 = MFMA16(ax[1][1], b1, c1);
    float bias = bgAll[g * 128 + nt * 16 + lm];
#pragma unroll
    for (int r = 0; r < 4; r++) {
      CONV_s[(w32 + q * 4 + r) * SH + nt * 16 + lm] = f2bf(c0[r] + bias);
      CONV_s[(w32 + 16 + q * 4 + r) * SH + nt * 16 + lm] = f2bf(c1[r] + bias);
    }
  }
}

__device__ __forceinline__ void gate_gemm(int g, const u16* lowbuf, const u16* highbuf,
                                          const u16* __restrict__ wlB,
                                          const float* __restrict__ blAll,
                                          int w32, int lane, float out[2][8][4]) {
  const int q = lane >> 4, lm = lane & 15;
  short8 al[2][8];
#pragma unroll
  for (int s = 0; s < 2; s++) {
    int rb = (w32 + s * 16 + lm) * SH + q * 8;
#pragma unroll
    for (int kt = 0; kt < 4; kt++) al[s][kt] = *(const short8*)&lowbuf[rb + kt * 32];
#pragma unroll
    for (int kt = 0; kt < 4; kt++) al[s][4 + kt] = *(const short8*)&highbuf[rb + kt * 32];
  }
#pragma unroll
  for (int nt = 0; nt < 8; nt++) {
    floatx4 a0 = {0.f, 0.f, 0.f, 0.f}, a1 = {0.f, 0.f, 0.f, 0.f};
#pragma unroll
    for (int kt = 0; kt < 8; kt++) {
      short8 bfrag = *(const short8*)(wlB + (size_t)((g * 64 + kt * 8 + nt) * 64 + lane) * 8);
      a0 = MFMA16(al[0][kt], bfrag, a0);
      a1 = MFMA16(al[1][kt], bfrag, a1);
    }
    float bias = blAll[g * 128 + nt * 16 + lm];
#pragma unroll
    for (int r = 0; r < 4; r++) {
      out[0][nt][r] = a0[r] + bias;
      out[1][nt][r] = a1[r] + bias;
    }
  }
}

__global__ __launch_bounds__(128, 2) void fused_mfma(
    const u16* __restrict__ xs, const float* __restrict__ H,
    const u16* __restrict__ wgB, const u16* __restrict__ wlB,
    const float* __restrict__ bgAll, const float* __restrict__ blAll,
    float* __restrict__ hnew, float* __restrict__ msum) {
  __shared__ u16 HT_s[64 * SH];    // H tile, bf16
  __shared__ u16 CONV_s[64 * SH];  // conv_g buffer (reused z -> r -> h)
  __shared__ u16 XHR_s[64 * SH];   // union: xs tile (stride SX) then H*R (stride SH)

  const int tid = threadIdx.x;
  const int b = blockIdx.y;
  const int n0 = blockIdx.x * 64;
  const int lane = tid & 63, w = tid >> 6;
  const int q = lane >> 4, lm = lane & 15;
  const int w32 = w * 32;

  // ---- stage xs tile (bf16, rows masked to zero past N) ----
#pragma unroll
  for (int i = 0; i < 4; i++) {
    int idx = i * 128 + tid;  // 0..511: row(64) x seg(8)
    int row = idx >> 3, seg = idx & 7;
    uint4 v = make_uint4(0u, 0u, 0u, 0u);
    if (n0 + row < N) v = *(const uint4*)(xs + ((size_t)b * N + n0 + row) * DIN + seg * 8);
    *(uint4*)&XHR_s[row * SX + seg * 8] = v;
  }
  // ---- stage H tile fp32 -> bf16 ----
#pragma unroll
  for (int i = 0; i < 16; i++) {
    int idx = i * 128 + tid;  // 0..2047: row(64) x seg(32)
    int row = idx >> 5, seg = idx & 31;
    float4 v = make_float4(0.f, 0.f, 0.f, 0.f);
    if (n0 + row < N) v = *(const float4*)(H + ((size_t)b * N + n0 + row) * DMID + seg * 4);
    uint2 p;
    p.x = (unsigned)f2bf(v.x) | ((unsigned)f2bf(v.y) << 16);
    p.y = (unsigned)f2bf(v.z) | ((unsigned)f2bf(v.w) << 16);
    *(uint2*)&HT_s[row * SH + seg * 4] = p;
  }
  __syncthreads();

  // xs A-frags (kept in regs; XHR_s gets overwritten by H*R later)
  short8 ax[2][2];
#pragma unroll
  for (int s = 0; s < 2; s++)
#pragma unroll
    for (int kt = 0; kt < 2; kt++)
      ax[s][kt] = *(const short8*)&XHR_s[(w32 + s * 16 + lm) * SX + kt * 32 + q * 8];

  float zacc[2][8][4], racc[2][8][4], hacc[2][8][4];

  conv_gemm(0, ax, wgB, bgAll, CONV_s, w32, lane);
  __syncthreads();
  gate_gemm(0, CONV_s, HT_s, wlB, blAll, w32, lane, zacc);
  __syncthreads();
  conv_gemm(1, ax, wgB, bgAll, CONV_s, w32, lane);
  __syncthreads();
  gate_gemm(1, CONV_s, HT_s, wlB, blAll, w32, lane, racc);
  __syncthreads();
  conv_gemm(2, ax, wgB, bgAll, CONV_s, w32, lane);
  // H*R -> XHR_s (each wave writes only its own rows)
#pragma unroll
  for (int s = 0; s < 2; s++)
#pragma unroll
    for (int nt = 0; nt < 8; nt++)
#pragma unroll
      for (int r = 0; r < 4; r++) {
        int row = w32 + s * 16 + q * 4 + r, col = nt * 16 + lm;
        float rg = sigmoid_fast(racc[s][nt][r]);
        float h = bf2f(HT_s[row * SH + col]);
        XHR_s[row * SH + col] = f2bf(h * rg);
      }
  __syncthreads();
  gate_gemm(2, CONV_s, XHR_s, wlB, blAll, w32, lane, hacc);

  // ---- epilogue: blend, store, mean-accumulate ----
#pragma unroll
  for (int s = 0; s < 2; s++)
#pragma unroll
    for (int nt = 0; nt < 8; nt++) {
      float colsum = 0.f;
#pragma unroll
      for (int r = 0; r < 4; r++) {
        int row = w32 + s * 16 + q * 4 + r;
        bool valid = (n0 + row) < N;
        float z = sigmoid_fast(zacc[s][nt][r]);
        float ht = tanh_fast(hacc[s][nt][r]);
        float h = bf2f(HT_s[row * SH + nt * 16 + lm]);
        float hn = fmaf(z, h - ht, ht);  // z*H + (1-z)*ht
        if (valid) {
          hnew[((size_t)b * N + n0 + row) * DMID + nt * 16 + lm] = hn;
          colsum += hn;
        }
      }
      colsum += __shfl_xor(colsum, 16);
      colsum += __shfl_xor(colsum, 32);
      if (lane < 16) atomicAdd(&msum[b * DMID + nt * 16 + lane], colsum);
    }
}

// ---------------- output head ----------------

__global__ void out_kernel(const float* __restrict__ msum, const float* __restrict__ Wout,
                           const float* __restrict__ bout, float* __restrict__ y) {
  const int b = blockIdx.x;
  const int o = threadIdx.x;  // 32 threads
  __shared__ float m[DMID];
  for (int jj = o; jj < DMID; jj += 32)
    m[jj] = fmaxf(msum[b * DMID + jj] * (1.f / (float)N), 0.f);
  __syncthreads();
  float acc = bout[o];
  for (int jj = 0; jj < DMID; jj++)
    acc = fmaf(m[jj], Wout[jj * DOUT + o], acc);
  y[b * DOUT + o] = acc;
}

}  // namespace

extern "C" void kernel_launch(void* const* d_in, const int* in_sizes, int n_in,
                              void* d_out, int out_size, void* d_ws, size_t ws_size,
                              hipStream_t stream) {
  const float* x = (const float*)d_in[0];
  const int* ei = (const int*)d_in[1];
  const float* H = (const float*)d_in[2];
  const float* Wgz = (const float*)d_in[3];
  const float* bgz = (const float*)d_in[4];
  const float* Wgr = (const float*)d_in[5];
  const float* bgr = (const float*)d_in[6];
  const float* Wgh = (const float*)d_in[7];
  const float* bgh = (const float*)d_in[8];
  const float* Wlz = (const float*)d_in[9];
  const float* blz = (const float*)d_in[10];
  const float* Wlr = (const float*)d_in[11];
  const float* blr = (const float*)d_in[12];
  const float* Wlh = (const float*)d_in[13];
  const float* blh = (const float*)d_in[14];
  const float* Wout = (const float*)d_in[15];
  const float* bout = (const float*)d_in[16];

  float* y = (float*)d_out;                        // [B, DOUT]
  float* hnew = (float*)d_out + (size_t)B * DOUT;  // [B, N, DMID]

  char* p = (char*)d_ws;
  auto carve = [&](size_t bytes) {
    char* q = p;
    p += (bytes + 255) & ~size_t(255);
    return q;
  };
  int* counts = (int*)carve((size_t)N * 4);
  int* rowptr = (int*)carve((size_t)(N + 1) * 4);
  int* fill = (int*)carve((size_t)N * 4);
  int* csr_src = (int*)carve((size_t)E * 4);
  float* csr_w = (float*)carve((size_t)E * 4);
  float* dis = (float*)carve((size_t)N * 4);
  float* msum = (float*)carve((size_t)B * DMID * 4);
  u16* wgB = (u16*)carve((size_t)48 * 64 * 8 * 2);
  u16* wlB = (u16*)carve((size_t)192 * 64 * 8 * 2);
  float* bgAll = (float*)carve((size_t)384 * 4);
  float* blAll = (float*)carve((size_t)384 * 4);
  u16* xs = (u16*)carve((size_t)B * N * DIN * 2);  // ~41 MB

  zero_kernel<<<(B * DMID + 255) / 256, 256, 0, stream>>>(counts, fill, msum);
  pack_kernel<<<63, 256, 0, stream>>>(Wgz, Wgr, Wgh, Wlz, Wlr, Wlh,
                                      bgz, bgr, bgh, blz, blr, blh,
                                      wgB, wlB, bgAll, blAll);
  count_kernel<<<(E + 255) / 256, 256, 0, stream>>>(ei, counts);
  scan_kernel<<<1, 1024, 0, stream>>>(counts, rowptr, dis);
  fill_kernel<<<(E + 255) / 256, 256, 0, stream>>>(ei, rowptr, dis, fill, csr_src, csr_w);
  agg_kernel<<<B * N / 4, 256, 0, stream>>>(x, rowptr, csr_src, csr_w, dis, xs);
  fused_mfma<<<dim3((N + 63) / 64, B), 128, 0, stream>>>(xs, H, wgB, wlB, bgAll, blAll,
                                                         hnew, msum);
  out_kernel<<<B, 32, 0, stream>>>(msum, Wout, bout, y);
}